// Round 1
// baseline (361.679 us; speedup 1.0000x reference)
//
#include <hip/hip_runtime.h>

#define NB 8192      // batch
#define DIM 2048     // input dim
// ws float offsets
static const size_t OFF_WCAT = 0;          // [2048][384]  = 786432
static const size_t OFF_H1T  = 786432;     // [256][8192]
static const size_t OFF_DH1T = 2883584;    // [256][8192]
static const size_t OFF_GH2T = 4980736;    // [128][8192]
static const size_t OFF_A2T  = 6029312;    // [128][8192]
static const size_t OFF_DA2T = 7077888;    // [128][8192]
static const size_t OFF_GA2T = 8126464;    // [128][8192]
static const size_t OFF_W2T  = 9175040;    // [128][256]
static const size_t OFF_W1P  = 9207808;    // [256]
static const size_t OFF_WOP  = 9208064;    // [128]
// total 9208192 floats = 36.8 MB of ws

// ---------------- prologues ----------------

// Wcat[d][n] = n<256 ? W1[d][n] : Wo[n-256][d]
__global__ void k_wcat(const float* __restrict__ W1, const float* __restrict__ Wo,
                       float* __restrict__ Wcat) {
  int idx = blockIdx.x * 256 + threadIdx.x;  // 786432 total
  int d = idx / 384, n = idx % 384;
  float v = (n < 256) ? W1[d * 256 + n] : Wo[(n - 256) * 2048 + d];
  Wcat[idx] = v;
}

// w1p[i] = sum_d W1[d][i] * Wp[d]   (partial per 64-row chunk, atomicAdd)
__global__ void k_w1p(const float* __restrict__ W1, const float* __restrict__ Wp,
                      float* __restrict__ w1p) {
  int i = threadIdx.x;          // 256
  int d0 = blockIdx.x * 64;     // 32 blocks
  float acc = 0.f;
  #pragma unroll 8
  for (int dd = 0; dd < 64; ++dd)
    acc = fmaf(W1[(d0 + dd) * 256 + i], Wp[d0 + dd], acc);
  atomicAdd(&w1p[i], acc);
}

// wop[j] = sum_d Wo[j][d] * Wp[d]   (block per j)
__global__ void k_wop(const float* __restrict__ Wo, const float* __restrict__ Wp,
                      float* __restrict__ wop) {
  int j = blockIdx.x;           // 128
  int t = threadIdx.x;          // 256
  float acc = 0.f;
  #pragma unroll
  for (int d = t; d < 2048; d += 256) acc = fmaf(Wo[j * 2048 + d], Wp[d], acc);
  __shared__ float red[256];
  red[t] = acc; __syncthreads();
  for (int s = 128; s > 0; s >>= 1) { if (t < s) red[t] += red[t + s]; __syncthreads(); }
  if (t == 0) wop[j] = red[0];
}

// W2T[j][i] = W2[i][j]
__global__ void k_w2t(const float* __restrict__ W2, float* __restrict__ W2T) {
  int idx = blockIdx.x * 256 + threadIdx.x;  // 32768
  int j = idx / 256, i = idx % 256;
  W2T[idx] = W2[i * 128 + j];
}

// ---------------- shared GEMM inner loop ----------------
// lane owns one m-row; wave owns 16 consecutive n-cols (uniform addr -> s_load)
template <int LDB>
__device__ __forceinline__ void compute_chunk(const float* __restrict__ B, int kc,
                                              int wn0u, int lane,
                                              const float* At, float* acc) {
  #pragma unroll 8
  for (int k = 0; k < 32; ++k) {
    float a = At[k * 65 + lane];
    const float* bp = B + (size_t)(kc + k) * LDB + wn0u;
    float4 q0 = *(const float4*)(bp);
    float4 q1 = *(const float4*)(bp + 4);
    float4 q2 = *(const float4*)(bp + 8);
    float4 q3 = *(const float4*)(bp + 12);
    acc[0]  = fmaf(a, q0.x, acc[0]);  acc[1]  = fmaf(a, q0.y, acc[1]);
    acc[2]  = fmaf(a, q0.z, acc[2]);  acc[3]  = fmaf(a, q0.w, acc[3]);
    acc[4]  = fmaf(a, q1.x, acc[4]);  acc[5]  = fmaf(a, q1.y, acc[5]);
    acc[6]  = fmaf(a, q1.z, acc[6]);  acc[7]  = fmaf(a, q1.w, acc[7]);
    acc[8]  = fmaf(a, q2.x, acc[8]);  acc[9]  = fmaf(a, q2.y, acc[9]);
    acc[10] = fmaf(a, q2.z, acc[10]); acc[11] = fmaf(a, q2.w, acc[11]);
    acc[12] = fmaf(a, q3.x, acc[12]); acc[13] = fmaf(a, q3.y, acc[13]);
    acc[14] = fmaf(a, q3.z, acc[14]); acc[15] = fmaf(a, q3.w, acc[15]);
  }
}

// ---------------- GEMM1: [H1t,DH1t,GH2t] from X @ Wcat ----------------
// grid (128, 6), block 256. BM=64 BN=64 BK=32, K=2048.
__global__ __launch_bounds__(256) void k_gemm1(
    const float* __restrict__ X, const float* __restrict__ Wcat,
    const float* __restrict__ b1, float* __restrict__ H1t,
    float* __restrict__ DH1t, float* __restrict__ GH2t) {
  __shared__ float At[32 * 65];
  const int m0 = blockIdx.x * 64;
  const int n0 = blockIdx.y * 64;
  const int lane = threadIdx.x & 63;
  const int wn0u = __builtin_amdgcn_readfirstlane(n0 + (threadIdx.x >> 6) * 16);
  float acc[16];
  #pragma unroll
  for (int i = 0; i < 16; ++i) acc[i] = 0.f;

  const int r = threadIdx.x >> 2;   // 0..63 (row)
  const int kq = threadIdx.x & 3;   // 0..3  (k-octet)
  const float* xbase = X + (size_t)(m0 + r) * DIM + kq * 8;
  float4 p0 = *(const float4*)(xbase);
  float4 p1 = *(const float4*)(xbase + 4);

  for (int kc = 0; kc < DIM; kc += 32) {
    __syncthreads();
    {
      int kb = kq * 8;
      At[(kb + 0) * 65 + r] = p0.x; At[(kb + 1) * 65 + r] = p0.y;
      At[(kb + 2) * 65 + r] = p0.z; At[(kb + 3) * 65 + r] = p0.w;
      At[(kb + 4) * 65 + r] = p1.x; At[(kb + 5) * 65 + r] = p1.y;
      At[(kb + 6) * 65 + r] = p1.z; At[(kb + 7) * 65 + r] = p1.w;
    }
    __syncthreads();
    if (kc + 32 < DIM) {   // prefetch next chunk under compute
      p0 = *(const float4*)(xbase + kc + 32);
      p1 = *(const float4*)(xbase + kc + 36);
    }
    compute_chunk<384>(Wcat, kc, wn0u, lane, At, acc);
  }

  const int row = m0 + lane;
  if (n0 < 256) {
    #pragma unroll
    for (int j = 0; j < 16; ++j) {
      int n = wn0u + j;
      float pre = acc[j];            // z@W1 col n  (== da1)
      float a1 = pre + b1[n];
      H1t[n * NB + row] = fmaxf(a1, 0.f);
      DH1t[n * NB + row] = a1 > 0.f ? pre : 0.f;
    }
  } else {
    #pragma unroll
    for (int j = 0; j < 16; ++j) {
      int n = wn0u + j - 256;
      GH2t[n * NB + row] = acc[j];   // g_h2 = z @ Wo^T
    }
  }
}

// ---------------- GEMM2: A2t = H1t@W2, DA2t = DH1t@W2 ----------------
// grid (256, 2): x<128 -> H1t, else DH1t. K=256, N=128.
__global__ __launch_bounds__(256) void k_gemm2(
    const float* __restrict__ H1t, const float* __restrict__ DH1t,
    const float* __restrict__ W2, float* __restrict__ A2t,
    float* __restrict__ DA2t) {
  __shared__ float At[32 * 65];
  const int mat = blockIdx.x >> 7;
  const int m0 = (blockIdx.x & 127) * 64;
  const int n0 = blockIdx.y * 64;
  const float* A = mat ? DH1t : H1t;
  float* C = mat ? DA2t : A2t;
  const int lane = threadIdx.x & 63;
  const int wn0u = __builtin_amdgcn_readfirstlane(n0 + (threadIdx.x >> 6) * 16);
  float acc[16];
  #pragma unroll
  for (int i = 0; i < 16; ++i) acc[i] = 0.f;

  const int kk = threadIdx.x >> 4;  // 0..15
  const int mq = threadIdx.x & 15;  // 0..15
  const float* abase = A + (size_t)kk * NB + m0 + mq * 4;
  float4 p0 = *(const float4*)(abase);
  float4 p1 = *(const float4*)(abase + (size_t)16 * NB);

  for (int kc = 0; kc < 256; kc += 32) {
    __syncthreads();
    At[kk * 65 + mq * 4 + 0] = p0.x; At[kk * 65 + mq * 4 + 1] = p0.y;
    At[kk * 65 + mq * 4 + 2] = p0.z; At[kk * 65 + mq * 4 + 3] = p0.w;
    At[(kk + 16) * 65 + mq * 4 + 0] = p1.x; At[(kk + 16) * 65 + mq * 4 + 1] = p1.y;
    At[(kk + 16) * 65 + mq * 4 + 2] = p1.z; At[(kk + 16) * 65 + mq * 4 + 3] = p1.w;
    __syncthreads();
    if (kc + 32 < 256) {
      p0 = *(const float4*)(abase + (size_t)(kc + 32) * NB);
      p1 = *(const float4*)(abase + (size_t)(kc + 48) * NB);
    }
    compute_chunk<128>(W2, kc, wn0u, lane, At, acc);
  }
  const int row = m0 + lane;
  #pragma unroll
  for (int j = 0; j < 16; ++j) C[(wn0u + j) * NB + row] = acc[j];
}

// ---------------- mid: mask2, jx, GA2t, OUT = jx + bp ----------------
__global__ void k_mid(const float* __restrict__ A2t, const float* __restrict__ DA2t,
                      const float* __restrict__ GH2t, const float* __restrict__ b2,
                      const float* __restrict__ wop, const float* __restrict__ bp,
                      float* __restrict__ GA2t, float* __restrict__ OUT) {
  int s = blockIdx.x * 64 + threadIdx.x;  // grid 128, block 64
  float jx = 0.f;
  #pragma unroll 8
  for (int j = 0; j < 128; ++j) {
    float a2 = A2t[j * NB + s] + b2[j];
    float da2 = DA2t[j * NB + s];
    float gh2 = GH2t[j * NB + s];
    bool m2 = a2 > 0.f;
    jx = fmaf(m2 ? da2 : 0.f, wop[j], jx);
    GA2t[j * NB + s] = m2 ? gh2 : 0.f;
  }
  OUT[s] = jx + bp[0];
}

// ---------------- GEMM3: g_h1 = GA2t @ W2T; fused jtx epilogue ----------------
// grid (128, 4). K=128, N=256. OUT -= g_a1 . w1p  (atomic)
__global__ __launch_bounds__(256) void k_gemm3(
    const float* __restrict__ GA2t, const float* __restrict__ W2T,
    const float* __restrict__ H1t, const float* __restrict__ w1p,
    float* OUT) {
  __shared__ float At[32 * 65];
  const int m0 = blockIdx.x * 64;
  const int n0 = blockIdx.y * 64;
  const int lane = threadIdx.x & 63;
  const int wn0u = __builtin_amdgcn_readfirstlane(n0 + (threadIdx.x >> 6) * 16);
  float acc[16];
  #pragma unroll
  for (int i = 0; i < 16; ++i) acc[i] = 0.f;

  const int kk = threadIdx.x >> 4;
  const int mq = threadIdx.x & 15;
  const float* abase = GA2t + (size_t)kk * NB + m0 + mq * 4;
  float4 p0 = *(const float4*)(abase);
  float4 p1 = *(const float4*)(abase + (size_t)16 * NB);

  for (int kc = 0; kc < 128; kc += 32) {
    __syncthreads();
    At[kk * 65 + mq * 4 + 0] = p0.x; At[kk * 65 + mq * 4 + 1] = p0.y;
    At[kk * 65 + mq * 4 + 2] = p0.z; At[kk * 65 + mq * 4 + 3] = p0.w;
    At[(kk + 16) * 65 + mq * 4 + 0] = p1.x; At[(kk + 16) * 65 + mq * 4 + 1] = p1.y;
    At[(kk + 16) * 65 + mq * 4 + 2] = p1.z; At[(kk + 16) * 65 + mq * 4 + 3] = p1.w;
    __syncthreads();
    if (kc + 32 < 128) {
      p0 = *(const float4*)(abase + (size_t)(kc + 32) * NB);
      p1 = *(const float4*)(abase + (size_t)(kc + 48) * NB);
    }
    compute_chunk<256>(W2T, kc, wn0u, lane, At, acc);
  }

  const int row = m0 + lane;
  float part = 0.f;
  #pragma unroll
  for (int j = 0; j < 16; ++j) {
    int n = wn0u + j;
    bool m1 = H1t[n * NB + row] > 0.f;   // mask1 (h1>0 <=> a1>0)
    part = fmaf(m1 ? acc[j] : 0.f, w1p[n], part);
  }
  atomicAdd(&OUT[row], -part);
}

extern "C" void kernel_launch(void* const* d_in, const int* in_sizes, int n_in,
                              void* d_out, int out_size, void* d_ws, size_t ws_size,
                              hipStream_t stream) {
  (void)in_sizes; (void)n_in; (void)out_size; (void)ws_size;
  const float* x  = (const float*)d_in[0];
  const float* W1 = (const float*)d_in[1];
  const float* b1 = (const float*)d_in[2];
  const float* W2 = (const float*)d_in[3];
  const float* b2 = (const float*)d_in[4];
  const float* Wo = (const float*)d_in[5];
  // d_in[6] = bo: unused (constant bias drops in both jvp and vjp)
  const float* Wp = (const float*)d_in[7];
  const float* bp = (const float*)d_in[8];
  float* ws = (float*)d_ws;
  float* OUT = (float*)d_out;

  hipMemsetAsync(ws + OFF_W1P, 0, 256 * sizeof(float), stream);
  k_wcat<<<3072, 256, 0, stream>>>(W1, Wo, ws + OFF_WCAT);
  k_w1p<<<32, 256, 0, stream>>>(W1, Wp, ws + OFF_W1P);
  k_wop<<<128, 256, 0, stream>>>(Wo, Wp, ws + OFF_WOP);
  k_w2t<<<128, 256, 0, stream>>>(W2, ws + OFF_W2T);
  k_gemm1<<<dim3(128, 6), 256, 0, stream>>>(x, ws + OFF_WCAT, b1,
                                            ws + OFF_H1T, ws + OFF_DH1T, ws + OFF_GH2T);
  k_gemm2<<<dim3(256, 2), 256, 0, stream>>>(ws + OFF_H1T, ws + OFF_DH1T, W2,
                                            ws + OFF_A2T, ws + OFF_DA2T);
  k_mid<<<128, 64, 0, stream>>>(ws + OFF_A2T, ws + OFF_DA2T, ws + OFF_GH2T,
                                b2, ws + OFF_WOP, bp, ws + OFF_GA2T, OUT);
  k_gemm3<<<dim3(128, 4), 256, 0, stream>>>(ws + OFF_GA2T, ws + OFF_W2T,
                                            ws + OFF_H1T, ws + OFF_W1P, OUT);
}

// Round 2
// 194.963 us; speedup vs baseline: 1.8551x; 1.8551x over previous
//
#include <hip/hip_runtime.h>

typedef _Float16 f16;
typedef _Float16 f16x8 __attribute__((ext_vector_type(8)));
typedef float f32x4 __attribute__((ext_vector_type(4)));

#define NB 8192
#define DIM 2048

// ---- workspace byte offsets ----
#define OFF_PRE1   0u           // f32 [8192][256]  (atomic-accumulated)
#define OFF_GH2    8388608u     // f32 [8192][128]
#define OFF_W1P    12582912u    // f32 [256] (atomic)
#define OFF_WOP    12583936u    // f32 [128]
#define OFF_W1HP   12584448u    // f16 pack [16nt][64kc][64lane][8]
#define OFF_W1LP   13633024u
#define OFF_WOTHP  14681600u    // f16 pack [8][64][64][8]
#define OFF_W2HP   15205888u    // f16 pack [8][8][64][8]
#define OFF_W2LP   15271424u
#define OFF_W2THP  15336960u    // f16 pack [16][4][64][8]
#define OFF_H1H    15402496u    // f16 [8192][256]
#define OFF_H1L    19596800u
#define OFF_DH1H   23791104u
#define OFF_GH2H   27985408u    // f16 [8192][128]
#define OFF_GA2H   30082560u    // f16 [8192][128]
#define OFF_M1     32179712u    // u8  [8192][32]

__device__ __forceinline__ f16 hi16(float x) { return (f16)x; }
__device__ __forceinline__ f16 lo16(float x, f16 h) { return (f16)(x - (float)h); }

// ---------------- pack kernel: fragment-major fp16 hi/lo weights ----------------
// ranges (threads): W1 hi+lo 65536 | WoT hi 32768 | W2 hi+lo 4096 | W2T hi 4096
__global__ void k_pack(const float* __restrict__ W1, const float* __restrict__ Wo,
                       const float* __restrict__ W2, f16* __restrict__ W1h,
                       f16* __restrict__ W1l, f16* __restrict__ WoTh,
                       f16* __restrict__ W2h, f16* __restrict__ W2l,
                       f16* __restrict__ W2Th) {
  int tid = blockIdx.x * 256 + threadIdx.x;   // 106496 total
  int g, c, kc, nt;
  if (tid < 65536) {                 // W1: KC=64, NT=16
    int cid = tid; int lane = cid & 63; int kcnt = cid >> 6;
    kc = kcnt & 63; nt = kcnt >> 6; g = lane >> 4; c = lane & 15;
    f16x8 h8, l8;
    #pragma unroll
    for (int j = 0; j < 8; ++j) {
      float v = W1[(size_t)(kc * 32 + 8 * g + j) * 256 + nt * 16 + c];
      f16 h = hi16(v); h8[j] = h; l8[j] = lo16(v, h);
    }
    *(f16x8*)&W1h[(size_t)cid * 8] = h8;
    *(f16x8*)&W1l[(size_t)cid * 8] = l8;
  } else if (tid < 98304) {          // WoT: KC=64, NT=8
    int cid = tid - 65536; int lane = cid & 63; int kcnt = cid >> 6;
    kc = kcnt & 63; nt = kcnt >> 6; g = lane >> 4; c = lane & 15;
    f16x8 h8;
    #pragma unroll
    for (int j = 0; j < 8; ++j)
      h8[j] = hi16(Wo[(size_t)(nt * 16 + c) * 2048 + kc * 32 + 8 * g + j]);
    *(f16x8*)&WoTh[(size_t)cid * 8] = h8;
  } else if (tid < 102400) {         // W2: KC=8, NT=8
    int cid = tid - 98304; int lane = cid & 63; int kcnt = cid >> 6;
    kc = kcnt & 7; nt = kcnt >> 3; g = lane >> 4; c = lane & 15;
    f16x8 h8, l8;
    #pragma unroll
    for (int j = 0; j < 8; ++j) {
      float v = W2[(size_t)(kc * 32 + 8 * g + j) * 128 + nt * 16 + c];
      f16 h = hi16(v); h8[j] = h; l8[j] = lo16(v, h);
    }
    *(f16x8*)&W2h[(size_t)cid * 8] = h8;
    *(f16x8*)&W2l[(size_t)cid * 8] = l8;
  } else if (tid < 106496) {         // W2T: KC=4, NT=16
    int cid = tid - 102400; int lane = cid & 63; int kcnt = cid >> 6;
    kc = kcnt & 3; nt = kcnt >> 2; g = lane >> 4; c = lane & 15;
    f16x8 h8;
    #pragma unroll
    for (int j = 0; j < 8; ++j)
      h8[j] = hi16(W2[(size_t)(nt * 16 + c) * 128 + kc * 32 + 8 * g + j]);
    *(f16x8*)&W2Th[(size_t)cid * 8] = h8;
  }
}

// w1p[i] = sum_d W1[d][i]*Wp[d]  (atomic partials; w1p pre-zeroed)
__global__ void k_w1p(const float* __restrict__ W1, const float* __restrict__ Wp,
                      float* __restrict__ w1p) {
  int i = threadIdx.x; int d0 = blockIdx.x * 64;
  float acc = 0.f;
  #pragma unroll 8
  for (int dd = 0; dd < 64; ++dd)
    acc = fmaf(W1[(size_t)(d0 + dd) * 256 + i], Wp[d0 + dd], acc);
  atomicAdd(&w1p[i], acc);
}

// wop[j] = sum_d Wo[j][d]*Wp[d]
__global__ void k_wop(const float* __restrict__ Wo, const float* __restrict__ Wp,
                      float* __restrict__ wop) {
  int j = blockIdx.x; int t = threadIdx.x;
  float acc = 0.f;
  #pragma unroll
  for (int d = t; d < 2048; d += 256) acc = fmaf(Wo[(size_t)j * 2048 + d], Wp[d], acc);
  __shared__ float red[256];
  red[t] = acc; __syncthreads();
  for (int s = 128; s > 0; s >>= 1) { if (t < s) red[t] += red[t + s]; __syncthreads(); }
  if (t == 0) wop[j] = red[0];
}

// ---------------- k_big: X @ [W1 (split, 3-pass) | WoT (single)] ----------------
// grid (128, 4): ny 0/1 = W1 cols, k-half ny; ny 2/3 = WoT cols, k-half ny-2.
// block 256 = 4 waves. BM=64. heavy wave: 64 cols (4 nt). light wave: 32 cols (2 nt).
// LDS: Xhi/Xlo fp16 [64 rows][256 k], XOR-swizzled in 16B octets.
__device__ __forceinline__ int aswz(int row, int o) {  // f16 offset of octet
  return (row * 32 + (o ^ (row & 15))) * 8;
}

__global__ __launch_bounds__(256) void k_big(
    const float* __restrict__ X, const f16* __restrict__ W1h,
    const f16* __restrict__ W1l, const f16* __restrict__ WoTh,
    float* __restrict__ pre1, float* __restrict__ gh2) {
  __shared__ f16 Ah[64 * 256];
  __shared__ f16 Al[64 * 256];
  const int ny = blockIdx.y;
  const bool heavy = ny < 2;
  const int k0 = (heavy ? ny : ny - 2) * 1024;
  const int m0 = blockIdx.x * 64;
  const int w = threadIdx.x >> 6;
  const int lane = threadIdx.x & 63;
  const int g = lane >> 4, c = lane & 15;

  f32x4 acc[4][4];
  #pragma unroll
  for (int a = 0; a < 4; ++a)
    #pragma unroll
    for (int b = 0; b < 4; ++b) acc[a][b] = (f32x4)0.f;

  const int r = threadIdx.x >> 2;        // staging row 0..63
  const int seg = threadIdx.x & 3;       // 64-float segment
  const float4* X4 = (const float4*)X;

  for (int sc = 0; sc < 4; ++sc) {
    // ---- stage: X fp32 -> hi/lo fp16 into swizzled LDS ----
    {
      size_t base = (size_t)(m0 + r) * 512 + (size_t)(k0 + sc * 256 + seg * 64) / 4;
      #pragma unroll
      for (int i = 0; i < 8; ++i) {
        float4 qa = X4[base + i * 2];
        float4 qb = X4[base + i * 2 + 1];
        float q[8] = {qa.x, qa.y, qa.z, qa.w, qb.x, qb.y, qb.z, qb.w};
        f16x8 h8, l8;
        #pragma unroll
        for (int j = 0; j < 8; ++j) {
          f16 h = hi16(q[j]); h8[j] = h;
          l8[j] = lo16(q[j], h);
        }
        int o = seg * 8 + i;
        int a = aswz(r, o);
        *(f16x8*)&Ah[a] = h8;
        if (heavy) *(f16x8*)&Al[a] = l8;
      }
    }
    __syncthreads();
    // ---- compute 8 k-chunks of 32 ----
    const int kcib = (heavy ? ny : ny - 2) * 32 + sc * 8;  // global k-chunk base
    if (heavy) {
      #pragma unroll 2
      for (int kc = 0; kc < 8; ++kc) {
        f16x8 bh[4], bl[4], ah[4], al[4];
        #pragma unroll
        for (int nt = 0; nt < 4; ++nt) {
          size_t idx = ((size_t)(w * 4 + nt) * 64 + (kcib + kc)) * 64 + lane;
          bh[nt] = *(const f16x8*)&W1h[idx * 8];
          bl[nt] = *(const f16x8*)&W1l[idx * 8];
        }
        #pragma unroll
        for (int mt = 0; mt < 4; ++mt) {
          int a = aswz(c + 16 * mt, kc * 4 + g);
          ah[mt] = *(const f16x8*)&Ah[a];
          al[mt] = *(const f16x8*)&Al[a];
        }
        #pragma unroll
        for (int mt = 0; mt < 4; ++mt)
          #pragma unroll
          for (int nt = 0; nt < 4; ++nt) {
            acc[mt][nt] = __builtin_amdgcn_mfma_f32_16x16x32_f16(ah[mt], bh[nt], acc[mt][nt], 0, 0, 0);
            acc[mt][nt] = __builtin_amdgcn_mfma_f32_16x16x32_f16(ah[mt], bl[nt], acc[mt][nt], 0, 0, 0);
            acc[mt][nt] = __builtin_amdgcn_mfma_f32_16x16x32_f16(al[mt], bh[nt], acc[mt][nt], 0, 0, 0);
          }
      }
    } else {
      #pragma unroll 2
      for (int kc = 0; kc < 8; ++kc) {
        f16x8 bh[2], ah[4];
        #pragma unroll
        for (int nt = 0; nt < 2; ++nt) {
          size_t idx = ((size_t)(w * 2 + nt) * 64 + (kcib + kc)) * 64 + lane;
          bh[nt] = *(const f16x8*)&WoTh[idx * 8];
        }
        #pragma unroll
        for (int mt = 0; mt < 4; ++mt) {
          int a = aswz(c + 16 * mt, kc * 4 + g);
          ah[mt] = *(const f16x8*)&Ah[a];
        }
        #pragma unroll
        for (int mt = 0; mt < 4; ++mt)
          #pragma unroll
          for (int nt = 0; nt < 2; ++nt)
            acc[mt][nt] = __builtin_amdgcn_mfma_f32_16x16x32_f16(ah[mt], bh[nt], acc[mt][nt], 0, 0, 0);
      }
    }
    __syncthreads();
  }

  // ---- epilogue: atomic-accumulate fp32 partials ----
  if (heavy) {
    #pragma unroll
    for (int mt = 0; mt < 4; ++mt)
      #pragma unroll
      for (int nt = 0; nt < 4; ++nt)
        #pragma unroll
        for (int rr = 0; rr < 4; ++rr) {
          int row = m0 + 16 * mt + 4 * g + rr;
          int col = w * 64 + nt * 16 + c;
          atomicAdd(&pre1[(size_t)row * 256 + col], acc[mt][nt][rr]);
        }
  } else {
    #pragma unroll
    for (int mt = 0; mt < 4; ++mt)
      #pragma unroll
      for (int nt = 0; nt < 2; ++nt)
        #pragma unroll
        for (int rr = 0; rr < 4; ++rr) {
          int row = m0 + 16 * mt + 4 * g + rr;
          int col = w * 32 + nt * 16 + c;
          atomicAdd(&gh2[(size_t)row * 128 + col], acc[mt][nt][rr]);
        }
  }
}

// ---------------- k_mid1: a1 -> h1 hi/lo, dh1, mask bits; gh2 -> f16; OUT=bp ----------------
// thread idx: row = idx/48; slot = idx%48; slot<32 -> a1 cols slot*8..+7; else gh2 cols.
__global__ void k_mid1(const float* __restrict__ pre1, const float* __restrict__ gh2,
                       const float* __restrict__ b1, const float* __restrict__ bp,
                       f16* __restrict__ h1h, f16* __restrict__ h1l,
                       f16* __restrict__ dh1h, f16* __restrict__ gh2h,
                       unsigned char* __restrict__ M1, float* __restrict__ OUT) {
  int idx = blockIdx.x * 256 + threadIdx.x;   // 8192*48
  int row = idx / 48, slot = idx % 48;
  if (slot < 32) {
    int c0 = slot * 8;
    const float4* p = (const float4*)&pre1[(size_t)row * 256 + c0];
    float4 pa = p[0], pb = p[1];
    const float4* bq = (const float4*)&b1[c0];
    float4 ba = bq[0], bb = bq[1];
    float pr[8] = {pa.x, pa.y, pa.z, pa.w, pb.x, pb.y, pb.z, pb.w};
    float bv[8] = {ba.x, ba.y, ba.z, ba.w, bb.x, bb.y, bb.z, bb.w};
    f16x8 hh, hl, dh;
    unsigned bits = 0;
    #pragma unroll
    for (int j = 0; j < 8; ++j) {
      float a1 = pr[j] + bv[j];
      bool m = a1 > 0.f;
      float h1 = m ? a1 : 0.f;
      f16 h = hi16(h1);
      hh[j] = h; hl[j] = lo16(h1, h);
      dh[j] = hi16(m ? pr[j] : 0.f);
      bits |= (unsigned)m << j;
    }
    *(f16x8*)&h1h[(size_t)row * 256 + c0] = hh;
    *(f16x8*)&h1l[(size_t)row * 256 + c0] = hl;
    *(f16x8*)&dh1h[(size_t)row * 256 + c0] = dh;
    M1[(size_t)row * 32 + slot] = (unsigned char)bits;
    if (slot == 0) OUT[row] = bp[0];
  } else {
    int c0 = (slot - 32) * 8;
    const float4* p = (const float4*)&gh2[(size_t)row * 128 + c0];
    float4 pa = p[0], pb = p[1];
    float pr[8] = {pa.x, pa.y, pa.z, pa.w, pb.x, pb.y, pb.z, pb.w};
    f16x8 hh;
    #pragma unroll
    for (int j = 0; j < 8; ++j) hh[j] = hi16(pr[j]);
    *(f16x8*)&gh2h[(size_t)row * 128 + c0] = hh;
  }
}

// ---------------- k_gemm2: a2 = h1@W2 (split) [mask], da2 = dh1@W2h; jx, ga2 ----------------
// grid 256 (BM=32), block 256 = 4 waves; wave: 32 rows x 32 cols (2mt x 2nt).
__global__ __launch_bounds__(256) void k_gemm2(
    const f16* __restrict__ h1h, const f16* __restrict__ h1l,
    const f16* __restrict__ dh1h, const f16* __restrict__ W2h,
    const f16* __restrict__ W2l, const f16* __restrict__ gh2h,
    const float* __restrict__ b2, const float* __restrict__ wop,
    f16* __restrict__ ga2h, float* __restrict__ OUT) {
  const int m0 = blockIdx.x * 32;
  const int w = threadIdx.x >> 6;
  const int lane = threadIdx.x & 63;
  const int g = lane >> 4, c = lane & 15;
  f32x4 a2[2][2], d2[2][2];
  #pragma unroll
  for (int a = 0; a < 2; ++a)
    #pragma unroll
    for (int b = 0; b < 2; ++b) { a2[a][b] = (f32x4)0.f; d2[a][b] = (f32x4)0.f; }

  #pragma unroll
  for (int kc = 0; kc < 8; ++kc) {
    f16x8 ah[2], al[2], ad[2], bh[2], bl[2];
    #pragma unroll
    for (int mt = 0; mt < 2; ++mt) {
      size_t off = (size_t)(m0 + c + 16 * mt) * 256 + kc * 32 + 8 * g;
      ah[mt] = *(const f16x8*)&h1h[off];
      al[mt] = *(const f16x8*)&h1l[off];
      ad[mt] = *(const f16x8*)&dh1h[off];
    }
    #pragma unroll
    for (int nt = 0; nt < 2; ++nt) {
      size_t idx = ((size_t)(2 * w + nt) * 8 + kc) * 64 + lane;
      bh[nt] = *(const f16x8*)&W2h[idx * 8];
      bl[nt] = *(const f16x8*)&W2l[idx * 8];
    }
    #pragma unroll
    for (int mt = 0; mt < 2; ++mt)
      #pragma unroll
      for (int nt = 0; nt < 2; ++nt) {
        a2[mt][nt] = __builtin_amdgcn_mfma_f32_16x16x32_f16(ah[mt], bh[nt], a2[mt][nt], 0, 0, 0);
        a2[mt][nt] = __builtin_amdgcn_mfma_f32_16x16x32_f16(ah[mt], bl[nt], a2[mt][nt], 0, 0, 0);
        a2[mt][nt] = __builtin_amdgcn_mfma_f32_16x16x32_f16(al[mt], bh[nt], a2[mt][nt], 0, 0, 0);
        d2[mt][nt] = __builtin_amdgcn_mfma_f32_16x16x32_f16(ad[mt], bh[nt], d2[mt][nt], 0, 0, 0);
      }
  }
  // epilogue: mask2, jx partial, ga2 store
  #pragma unroll
  for (int mt = 0; mt < 2; ++mt)
    #pragma unroll
    for (int rr = 0; rr < 4; ++rr) {
      int row = m0 + 16 * mt + 4 * g + rr;
      float s = 0.f;
      #pragma unroll
      for (int nt = 0; nt < 2; ++nt) {
        int col = 32 * w + 16 * nt + c;
        float a2v = a2[mt][nt][rr] + b2[col];
        bool m2 = a2v > 0.f;
        f16 gv = gh2h[(size_t)row * 128 + col];
        ga2h[(size_t)row * 128 + col] = m2 ? gv : (f16)0.f;
        if (m2) s += d2[mt][nt][rr] * wop[col];
      }
      s += __shfl_xor(s, 1, 16); s += __shfl_xor(s, 2, 16);
      s += __shfl_xor(s, 4, 16); s += __shfl_xor(s, 8, 16);
      if (c == 0) atomicAdd(&OUT[row], s);
    }
}

// ---------------- k_gemm3: gh1 = ga2 @ W2T; OUT -= (mask1 .* gh1) . w1p ----------------
// grid 256 (BM=32), block 256 = 4 waves; wave: 32 rows x 64 cols (2mt x 4nt).
__global__ __launch_bounds__(256) void k_gemm3(
    const f16* __restrict__ ga2h, const f16* __restrict__ W2Th,
    const unsigned char* __restrict__ M1, const float* __restrict__ w1p,
    float* __restrict__ OUT) {
  const int m0 = blockIdx.x * 32;
  const int w = threadIdx.x >> 6;
  const int lane = threadIdx.x & 63;
  const int g = lane >> 4, c = lane & 15;
  f32x4 g1[2][4];
  #pragma unroll
  for (int a = 0; a < 2; ++a)
    #pragma unroll
    for (int b = 0; b < 4; ++b) g1[a][b] = (f32x4)0.f;

  #pragma unroll
  for (int kc = 0; kc < 4; ++kc) {
    f16x8 ga[2], bt[4];
    #pragma unroll
    for (int mt = 0; mt < 2; ++mt) {
      size_t off = (size_t)(m0 + c + 16 * mt) * 128 + kc * 32 + 8 * g;
      ga[mt] = *(const f16x8*)&ga2h[off];
    }
    #pragma unroll
    for (int nt = 0; nt < 4; ++nt) {
      size_t idx = ((size_t)(4 * w + nt) * 4 + kc) * 64 + lane;
      bt[nt] = *(const f16x8*)&W2Th[idx * 8];
    }
    #pragma unroll
    for (int mt = 0; mt < 2; ++mt)
      #pragma unroll
      for (int nt = 0; nt < 4; ++nt)
        g1[mt][nt] = __builtin_amdgcn_mfma_f32_16x16x32_f16(ga[mt], bt[nt], g1[mt][nt], 0, 0, 0);
  }
  #pragma unroll
  for (int mt = 0; mt < 2; ++mt)
    #pragma unroll
    for (int rr = 0; rr < 4; ++rr) {
      int row = m0 + 16 * mt + 4 * g + rr;
      float s = 0.f;
      #pragma unroll
      for (int nt = 0; nt < 4; ++nt) {
        int col = 64 * w + 16 * nt + c;
        unsigned bits = M1[(size_t)row * 32 + (col >> 3)];
        if ((bits >> (col & 7)) & 1) s += g1[mt][nt][rr] * w1p[col];
      }
      s += __shfl_xor(s, 1, 16); s += __shfl_xor(s, 2, 16);
      s += __shfl_xor(s, 4, 16); s += __shfl_xor(s, 8, 16);
      if (c == 0) atomicAdd(&OUT[row], -s);
    }
}

extern "C" void kernel_launch(void* const* d_in, const int* in_sizes, int n_in,
                              void* d_out, int out_size, void* d_ws, size_t ws_size,
                              hipStream_t stream) {
  (void)in_sizes; (void)n_in; (void)out_size; (void)ws_size;
  const float* x  = (const float*)d_in[0];
  const float* W1 = (const float*)d_in[1];
  const float* b1 = (const float*)d_in[2];
  const float* W2 = (const float*)d_in[3];
  const float* b2 = (const float*)d_in[4];
  const float* Wo = (const float*)d_in[5];
  // d_in[6] = bo: drops out of both jvp and vjp
  const float* Wp = (const float*)d_in[7];
  const float* bp = (const float*)d_in[8];
  char* ws = (char*)d_ws;
  float* OUT = (float*)d_out;

  float* pre1 = (float*)(ws + OFF_PRE1);
  float* gh2  = (float*)(ws + OFF_GH2);
  float* w1p  = (float*)(ws + OFF_W1P);
  float* wop  = (float*)(ws + OFF_WOP);
  f16* W1hP  = (f16*)(ws + OFF_W1HP);
  f16* W1lP  = (f16*)(ws + OFF_W1LP);
  f16* WoThP = (f16*)(ws + OFF_WOTHP);
  f16* W2hP  = (f16*)(ws + OFF_W2HP);
  f16* W2lP  = (f16*)(ws + OFF_W2LP);
  f16* W2ThP = (f16*)(ws + OFF_W2THP);
  f16* h1hA  = (f16*)(ws + OFF_H1H);
  f16* h1lA  = (f16*)(ws + OFF_H1L);
  f16* dh1hA = (f16*)(ws + OFF_DH1H);
  f16* gh2hA = (f16*)(ws + OFF_GH2H);
  f16* ga2hA = (f16*)(ws + OFF_GA2H);
  unsigned char* M1 = (unsigned char*)(ws + OFF_M1);

  // zero pre1 + gh2 + w1p (contiguous region)
  hipMemsetAsync(d_ws, 0, OFF_W1P + 1024, stream);
  k_pack<<<416, 256, 0, stream>>>(W1, Wo, W2, W1hP, W1lP, WoThP, W2hP, W2lP, W2ThP);
  k_w1p<<<32, 256, 0, stream>>>(W1, Wp, w1p);
  k_wop<<<128, 256, 0, stream>>>(Wo, Wp, wop);
  k_big<<<dim3(128, 4), 256, 0, stream>>>(x, W1hP, W1lP, WoThP, pre1, gh2);
  k_mid1<<<1536, 256, 0, stream>>>(pre1, gh2, b1, bp, h1hA, h1lA, dh1hA, gh2hA, M1, OUT);
  k_gemm2<<<256, 256, 0, stream>>>(h1hA, h1lA, dh1hA, W2hP, W2lP, gh2hA, b2, wop, ga2hA, OUT);
  k_gemm3<<<256, 256, 0, stream>>>(ga2hA, W2ThP, M1, w1p, OUT);
}